// Round 5
// baseline (258.379 us; speedup 1.0000x reference)
//
#include <hip/hip_runtime.h>

#define D 128
#define FCHUNK 2048

typedef float f32x4 __attribute__((ext_vector_type(4)));
typedef float f32x8 __attribute__((ext_vector_type(8)));
typedef short s16x8 __attribute__((ext_vector_type(8)));
typedef unsigned short u16x8 __attribute__((ext_vector_type(8)));

static __device__ __forceinline__ unsigned short f2bf(float f) {
    unsigned int u = __float_as_uint(f);
    unsigned int r = (u + 0x7FFFu + ((u >> 16) & 1u)) >> 16;  // RNE
    return (unsigned short)r;
}

// ===========================================================================
// ULTRA tier
// ===========================================================================

// hist (4-batched, no-return atomics) + feature->bf16 + W->Wt bf16, fused
__global__ void k_prep(const int* __restrict__ dst, int* __restrict__ cnt,
                       const float* __restrict__ feature,
                       unsigned short* __restrict__ fb, int E, int NF4,
                       const float* __restrict__ W,
                       unsigned short* __restrict__ wt) {
    int tid = blockIdx.x * blockDim.x + threadIdx.x;
    int stride = gridDim.x * blockDim.x;
    for (int base = tid * 4; base < E; base += stride * 4) {
        if (base + 4 <= E) {
            int4 d4 = *reinterpret_cast<const int4*>(dst + base);
            atomicAdd(&cnt[d4.x], 1);
            atomicAdd(&cnt[d4.y], 1);
            atomicAdd(&cnt[d4.z], 1);
            atomicAdd(&cnt[d4.w], 1);
        } else {
            for (int i = base; i < E; ++i) atomicAdd(&cnt[dst[i]], 1);
        }
    }
    const f32x4* f4 = reinterpret_cast<const f32x4*>(feature);
    ushort4* fb4 = reinterpret_cast<ushort4*>(fb);
    for (int i = tid; i < NF4; i += stride) {
        f32x4 v = f4[i];
        ushort4 o;
        o.x = f2bf(v[0]);
        o.y = f2bf(v[1]);
        o.z = f2bf(v[2]);
        o.w = f2bf(v[3]);
        fb4[i] = o;
    }
    for (int i = tid; i < D * D; i += stride) {
        int n = i >> 7, k = i & 127;
        wt[i] = f2bf(W[k * D + n]);
    }
}

// Node-ordered exclusive prefix scan of cnt -> offset/cursor.
// Decoupled lookback, ticket-ordered tiles (256 nodes/tile): deadlock-free
// even with limited residency. Sums < 2^30.
__global__ __launch_bounds__(256) void k_scan(const int* __restrict__ cnt,
                                              int* __restrict__ offset,
                                              int* __restrict__ cursor,
                                              int* __restrict__ ticket,
                                              unsigned int* __restrict__ flags,
                                              int N) {
    __shared__ int stile;
    __shared__ int wsum[4];
    __shared__ int sexcl;
    if (threadIdx.x == 0) stile = atomicAdd(ticket, 1);
    __syncthreads();
    int tile = stile;
    int i = tile * 256 + threadIdx.x;
    int lane = threadIdx.x & 63;
    int wv = threadIdx.x >> 6;
    int c = (i < N) ? cnt[i] : 0;
    int s = c;
    #pragma unroll
    for (int o = 1; o < 64; o <<= 1) {
        int t = __shfl_up(s, o);
        if (lane >= o) s += t;
    }
    if (lane == 63) wsum[wv] = s;
    __syncthreads();
    int wb = 0;
    for (int k = 0; k < wv; ++k) wb += wsum[k];
    int incl = s + wb;
    int tilesum = wsum[0] + wsum[1] + wsum[2] + wsum[3];
    if (threadIdx.x == 0) {
        if (tile == 0) {
            __atomic_store_n(&flags[0], 0x80000000u | (unsigned)tilesum,
                             __ATOMIC_RELEASE);
            sexcl = 0;
        } else {
            __atomic_store_n(&flags[tile], 0x40000000u | (unsigned)tilesum,
                             __ATOMIC_RELEASE);
            int excl = 0;
            int p = tile - 1;
            while (true) {
                unsigned f;
                do {
                    f = __atomic_load_n(&flags[p], __ATOMIC_ACQUIRE);
                } while (!(f & 0xC0000000u));
                excl += (int)(f & 0x3FFFFFFFu);
                if (f & 0x80000000u) break;
                --p;
            }
            __atomic_store_n(&flags[tile],
                             0x80000000u | (unsigned)(excl + tilesum),
                             __ATOMIC_RELEASE);
            sexcl = excl;
        }
    }
    __syncthreads();
    if (i < N) {
        int base = sexcl + incl - c;
        offset[i] = base;
        cursor[i] = base;
    }
}

// XCD-local fill: block discovers its physical XCD, drains that XCD's chunk
// queue over the edge list, keeping only edges whose dst-partition == XCD.
// Falls through to other queues afterwards (work stealing) so correctness
// never depends on the XCC_ID read. srcs/cursor lines then live in exactly
// one XCD L2 -> no cross-XCD dirty-line thrash.
__global__ __launch_bounds__(256) void k_fill_xcd(
    const int* __restrict__ src, const int* __restrict__ dst,
    int* __restrict__ cursor, unsigned short* __restrict__ srcs,
    int* __restrict__ q, int E, float scale8) {
    unsigned xcc = ((unsigned)__builtin_amdgcn_s_getreg(63508)) & 7u;
    int nchunk = (E + FCHUNK - 1) / FCHUNK;
    __shared__ int sc;
    for (int k = 0; k < 8; ++k) {
        int part = (int)((xcc + (unsigned)k) & 7u);
        while (true) {
            __syncthreads();
            if (threadIdx.x == 0) sc = atomicAdd(&q[part], 1);
            __syncthreads();
            int chunk = sc;
            if (chunk >= nchunk) break;
            int e0 = chunk * FCHUNK;
            int e1 = min(E, e0 + FCHUNK);
            for (int e = e0 + (int)threadIdx.x * 4; e < e1; e += 256 * 4) {
                if (e + 4 <= e1) {
                    int4 d4 = *reinterpret_cast<const int4*>(dst + e);
                    int4 s4 = *reinterpret_cast<const int4*>(src + e);
                    #pragma unroll
                    for (int u = 0; u < 4; ++u) {
                        int d = (&d4.x)[u];
                        int sv = (&s4.x)[u];
                        int p = min((int)((float)d * scale8), 7);
                        if (p == part) {
                            int pos = atomicAdd(&cursor[d], 1);
                            srcs[pos] = (unsigned short)sv;
                        }
                    }
                } else {
                    for (int i = e; i < e1; ++i) {
                        int d = dst[i];
                        int p = min((int)((float)d * scale8), 7);
                        if (p == part) {
                            int pos = atomicAdd(&cursor[d], 1);
                            srcs[pos] = (unsigned short)src[i];
                        }
                    }
                }
            }
        }
    }
}

static __device__ __forceinline__ void acc_bf16x8(f32x8& acc, u16x8 v) {
    #pragma unroll
    for (int i = 0; i < 8; ++i)
        acc[i] += __uint_as_float(((unsigned int)v[i]) << 16);
}

// aggregate from bf16 feature: one wave per node, 4 edges in flight
__global__ __launch_bounds__(256) void k_aggregate_u16(
    const unsigned short* __restrict__ fb,
    const unsigned short* __restrict__ srcs, const int* __restrict__ offset,
    const int* __restrict__ cnt, unsigned short* __restrict__ hb, int N) {
    int w = (blockIdx.x * blockDim.x + threadIdx.x) >> 6;
    int lane = threadIdx.x & 63;
    if (w >= N) return;
    int sub = lane >> 4;
    int l15 = lane & 15;
    int n = cnt[w];
    if (n == 0) {
        if (sub == 0) {
            u16x8 v = *reinterpret_cast<const u16x8*>(fb + (size_t)w * D + l15 * 8);
            *reinterpret_cast<u16x8*>(hb + (size_t)w * D + l15 * 8) = v;
        }
        return;
    }
    int base = offset[w];
    f32x8 acc = {0.f, 0.f, 0.f, 0.f, 0.f, 0.f, 0.f, 0.f};
    int j = 0;
    for (; j + 8 <= n; j += 8) {
        int s0 = srcs[base + j + sub];
        int s1 = srcs[base + j + 4 + sub];
        u16x8 v0 = *reinterpret_cast<const u16x8*>(fb + (size_t)s0 * D + l15 * 8);
        u16x8 v1 = *reinterpret_cast<const u16x8*>(fb + (size_t)s1 * D + l15 * 8);
        acc_bf16x8(acc, v0);
        acc_bf16x8(acc, v1);
    }
    for (; j < n; j += 4) {
        if (j + sub < n) {
            int s0 = srcs[base + j + sub];
            u16x8 v0 = *reinterpret_cast<const u16x8*>(fb + (size_t)s0 * D + l15 * 8);
            acc_bf16x8(acc, v0);
        }
    }
    #pragma unroll
    for (int i = 0; i < 8; ++i) acc[i] += __shfl_xor(acc[i], 16);
    #pragma unroll
    for (int i = 0; i < 8; ++i) acc[i] += __shfl_xor(acc[i], 32);
    if (sub == 0) {
        float r = 1.f / (float)n;
        u16x8 o;
        #pragma unroll
        for (int i = 0; i < 8; ++i) o[i] = f2bf(acc[i] * r);
        *reinterpret_cast<u16x8*>(hb + (size_t)w * D + l15 * 8) = o;
    }
}

// ===========================================================================
// Finalize GEMM: out = relu(h @ W + b). XOR-swizzled LDS, 16x16x32 MFMA.
// ===========================================================================
__global__ __launch_bounds__(256) void k_finalize_mfma(
    const unsigned short* __restrict__ hb, const unsigned short* __restrict__ Wt,
    const float* __restrict__ b, float* __restrict__ out, int N) {
    __shared__ char lds[65536];

    int t = threadIdx.x;
    int row0 = blockIdx.x * 128;

    #pragma unroll
    for (int i = 0; i < 8; ++i) {
        int chunk = i * 256 + t;
        int row = chunk >> 4;
        int c16 = chunk & 15;
        int ldsoff = row * 256 + ((c16 * 16) ^ ((row & 7) << 4));
        f32x4 v = {0.f, 0.f, 0.f, 0.f};
        int grow = row0 + row;
        if (grow < N)
            v = *reinterpret_cast<const f32x4*>(hb + (size_t)grow * D + c16 * 8);
        *reinterpret_cast<f32x4*>(&lds[ldsoff]) = v;
    }
    #pragma unroll
    for (int i = 0; i < 8; ++i) {
        int chunk = i * 256 + t;
        int row = chunk >> 4;
        int c16 = chunk & 15;
        int ldsoff = 32768 + row * 256 + ((c16 * 16) ^ ((row & 7) << 4));
        f32x4 v = *reinterpret_cast<const f32x4*>(Wt + (size_t)row * D + c16 * 8);
        *reinterpret_cast<f32x4*>(&lds[ldsoff]) = v;
    }
    __syncthreads();

    int wv = t >> 6;
    int l = t & 63;
    int l15 = l & 15;
    int lhi = l >> 4;

    f32x4 acc[2][8];
    #pragma unroll
    for (int m = 0; m < 2; ++m)
        #pragma unroll
        for (int n = 0; n < 8; ++n) acc[m][n] = (f32x4){0.f, 0.f, 0.f, 0.f};

    #pragma unroll
    for (int kk = 0; kk < 4; ++kk) {
        int kb = kk * 64 + lhi * 16;
        s16x8 af[2], bf[8];
        #pragma unroll
        for (int m = 0; m < 2; ++m) {
            int r = wv * 32 + m * 16 + l15;
            af[m] = *reinterpret_cast<const s16x8*>(
                &lds[r * 256 + (kb ^ ((r & 7) << 4))]);
        }
        #pragma unroll
        for (int n = 0; n < 8; ++n) {
            int r = n * 16 + l15;
            bf[n] = *reinterpret_cast<const s16x8*>(
                &lds[32768 + r * 256 + (kb ^ ((r & 7) << 4))]);
        }
        #pragma unroll
        for (int m = 0; m < 2; ++m)
            #pragma unroll
            for (int n = 0; n < 8; ++n)
                acc[m][n] = __builtin_amdgcn_mfma_f32_16x16x32_bf16(
                    af[m], bf[n], acc[m][n], 0, 0, 0);
    }

    #pragma unroll
    for (int n = 0; n < 8; ++n) {
        int col = n * 16 + l15;
        float bv = b[col];
        #pragma unroll
        for (int m = 0; m < 2; ++m) {
            int rbase = row0 + wv * 32 + m * 16 + lhi * 4;
            #pragma unroll
            for (int j = 0; j < 4; ++j) {
                int row = rbase + j;
                if (row < N)
                    out[(size_t)row * D + col] = fmaxf(acc[m][n][j] + bv, 0.f);
            }
        }
    }
}

// ===========================================================================
// Tier-2 kernels (fp32-feature gather, int srcs, unordered alloc)
// ===========================================================================
__global__ void k_hist(const int* __restrict__ dst, int* __restrict__ cnt,
                       int E) {
    int stride = gridDim.x * blockDim.x;
    for (int i = blockIdx.x * blockDim.x + threadIdx.x; i < E; i += stride)
        atomicAdd(&cnt[dst[i]], 1);
}

__global__ void k_alloc(const int* __restrict__ cnt, int* __restrict__ offset,
                        int* __restrict__ cursor, int* __restrict__ gtot,
                        int N, const float* __restrict__ W,
                        unsigned short* __restrict__ wt) {
    int i = blockIdx.x * blockDim.x + threadIdx.x;
    int lane = threadIdx.x & 63;
    if (W && i < D * D) {
        int n = i >> 7, k = i & 127;
        wt[i] = f2bf(W[k * D + n]);
    }
    int c = (i < N) ? cnt[i] : 0;
    int s = c;
    #pragma unroll
    for (int o = 1; o < 64; o <<= 1) {
        int t = __shfl_up(s, o);
        if (lane >= o) s += t;
    }
    int wavesum = __shfl(s, 63);
    int base = 0;
    if (lane == 0) base = atomicAdd(gtot, wavesum);
    base = __shfl(base, 0);
    if (i < N) {
        int off = base + s - c;
        offset[i] = off;
        cursor[i] = off;
    }
}

__global__ void k_fill(const int* __restrict__ src, const int* __restrict__ dst,
                       int* __restrict__ cursor, int* __restrict__ srcs,
                       int E) {
    int stride = gridDim.x * blockDim.x;
    for (int i = blockIdx.x * blockDim.x + threadIdx.x; i < E; i += stride) {
        int d = dst[i];
        int p = atomicAdd(&cursor[d], 1);
        srcs[p] = src[i];
    }
}

__global__ __launch_bounds__(256) void k_aggregate_bf16(
    const float* __restrict__ feature, const int* __restrict__ srcs,
    const int* __restrict__ offset, const int* __restrict__ cnt,
    unsigned short* __restrict__ hb, int N) {
    int w = (blockIdx.x * blockDim.x + threadIdx.x) >> 6;
    int lane = threadIdx.x & 63;
    if (w >= N) return;
    int sub = lane >> 5;
    int c0 = (lane & 31) * 4;
    int n = cnt[w];
    f32x4 acc = {0.f, 0.f, 0.f, 0.f};
    if (n == 0) {
        if (sub == 0)
            acc = *reinterpret_cast<const f32x4*>(feature + (size_t)w * D + c0);
    } else {
        int base = offset[w];
        int j = 0;
        for (; j + 4 <= n; j += 4) {
            int s0 = srcs[base + j + sub];
            int s1 = srcs[base + j + 2 + sub];
            f32x4 v0 = *reinterpret_cast<const f32x4*>(feature + (size_t)s0 * D + c0);
            f32x4 v1 = *reinterpret_cast<const f32x4*>(feature + (size_t)s1 * D + c0);
            acc += v0 + v1;
        }
        for (; j < n; j += 2) {
            if (j + sub < n) {
                int s0 = srcs[base + j + sub];
                f32x4 v0 = *reinterpret_cast<const f32x4*>(feature + (size_t)s0 * D + c0);
                acc += v0;
            }
        }
    }
    #pragma unroll
    for (int i = 0; i < 4; ++i) acc[i] += __shfl_xor(acc[i], 32);
    if (n > 1) {
        float r = 1.f / (float)n;
        #pragma unroll
        for (int i = 0; i < 4; ++i) acc[i] *= r;
    }
    if (sub == 0) {
        ushort4 o;
        o.x = f2bf(acc[0]);
        o.y = f2bf(acc[1]);
        o.z = f2bf(acc[2]);
        o.w = f2bf(acc[3]);
        *reinterpret_cast<ushort4*>(hb + (size_t)w * D + c0) = o;
    }
}

// ===========================================================================
// Tier-3/4 fallbacks
// ===========================================================================
__global__ __launch_bounds__(256) void k_aggregate_f32(
    const float* __restrict__ feature, const int* __restrict__ srcs,
    const int* __restrict__ offset, const int* __restrict__ cnt,
    float* __restrict__ h, int N) {
    int w = (blockIdx.x * blockDim.x + threadIdx.x) >> 6;
    int lane = threadIdx.x & 63;
    if (w >= N) return;
    int n = cnt[w];
    float2 acc = make_float2(0.f, 0.f);
    if (n == 0) {
        acc = *reinterpret_cast<const float2*>(feature + (size_t)w * D + lane * 2);
    } else {
        int base = offset[w];
        for (int j = 0; j < n; ++j) {
            int s0 = srcs[base + j];
            float2 v0 = *reinterpret_cast<const float2*>(feature + (size_t)s0 * D + lane * 2);
            acc.x += v0.x;
            acc.y += v0.y;
        }
        float r = 1.f / (float)n;
        acc.x *= r;
        acc.y *= r;
    }
    *reinterpret_cast<float2*>(h + (size_t)w * D + lane * 2) = acc;
}

__global__ void gcn_scatter(const float* __restrict__ feature,
                            const int* __restrict__ src,
                            const int* __restrict__ dst,
                            float* __restrict__ agg,
                            float* __restrict__ deg, int n_edges) {
    int gid = blockIdx.x * blockDim.x + threadIdx.x;
    int e = gid >> 6;
    int lane = gid & 63;
    if (e >= n_edges) return;
    int s = src[e];
    int d = dst[e];
    const float2 v =
        *reinterpret_cast<const float2*>(feature + (size_t)s * D + lane * 2);
    float* o = agg + (size_t)d * D + lane * 2;
    atomicAdd(o, v.x);
    atomicAdd(o + 1, v.y);
    if (lane == 0) atomicAdd(deg + d, 1.0f);
}

__global__ __launch_bounds__(256, 2) void gcn_finalize(
    float* __restrict__ inout, const float* __restrict__ feature,
    const float* __restrict__ W, const float* __restrict__ b,
    const float* __restrict__ deg, int n_nodes) {
    __shared__ float Ws[D * D];
    __shared__ float bs[D];
    __shared__ float hs[4][4][D];

    for (int i = threadIdx.x; i < (D * D) / 4; i += blockDim.x)
        reinterpret_cast<float4*>(Ws)[i] = reinterpret_cast<const float4*>(W)[i];
    if (threadIdx.x < D) bs[threadIdx.x] = b[threadIdx.x];
    __syncthreads();

    int wave = threadIdx.x >> 6;
    int lane = threadIdx.x & 63;
    int gwave = (blockIdx.x * blockDim.x + threadIdx.x) >> 6;
    int nwaves = (gridDim.x * blockDim.x) >> 6;
    int ngroups = (n_nodes + 3) / 4;

    for (int g = gwave; g < ngroups; g += nwaves) {
        int row0 = g * 4;
        #pragma unroll
        for (int r = 0; r < 4; ++r) {
            int row = row0 + r;
            if (row < n_nodes) {
                float2 h2;
                if (deg) {
                    float dg = deg[row];
                    if (dg > 0.f) {
                        float2 a = *reinterpret_cast<const float2*>(
                            inout + (size_t)row * D + lane * 2);
                        float rd = 1.f / dg;
                        h2.x = a.x * rd;
                        h2.y = a.y * rd;
                    } else {
                        h2 = *reinterpret_cast<const float2*>(
                            feature + (size_t)row * D + lane * 2);
                    }
                } else {
                    h2 = *reinterpret_cast<const float2*>(
                        inout + (size_t)row * D + lane * 2);
                }
                reinterpret_cast<float2*>(hs[wave][r])[lane] = h2;
            }
        }
        float acc2[4][2];
        #pragma unroll
        for (int r = 0; r < 4; ++r) {
            acc2[r][0] = bs[lane];
            acc2[r][1] = bs[lane + 64];
        }
        #pragma unroll 4
        for (int k = 0; k < D; ++k) {
            float w0 = Ws[k * D + lane];
            float w1 = Ws[k * D + lane + 64];
            #pragma unroll
            for (int r = 0; r < 4; ++r) {
                float hk = hs[wave][r][k];
                acc2[r][0] = fmaf(hk, w0, acc2[r][0]);
                acc2[r][1] = fmaf(hk, w1, acc2[r][1]);
            }
        }
        #pragma unroll
        for (int r = 0; r < 4; ++r) {
            int row = row0 + r;
            if (row < n_nodes) {
                inout[(size_t)row * D + lane] = fmaxf(acc2[r][0], 0.f);
                inout[(size_t)row * D + lane + 64] = fmaxf(acc2[r][1], 0.f);
            }
        }
    }
}

extern "C" void kernel_launch(void* const* d_in, const int* in_sizes, int n_in,
                              void* d_out, int out_size, void* d_ws,
                              size_t ws_size, hipStream_t stream) {
    const float* feature = (const float*)d_in[0];
    const float* W = (const float*)d_in[1];
    const float* b = (const float*)d_in[2];
    const int* src = (const int*)d_in[3];
    const int* dst = (const int*)d_in[4];
    int n_edges = in_sizes[3];
    int n_nodes = in_sizes[0] / D;

    float* out = (float*)d_out;
    int block = 256;
    int nrows_pad = ((n_nodes + 127) / 128) * 128;
    int nblk_scan = (n_nodes + 255) / 256;

    // ---- ULTRA layout (ints): cnt[N] | flags[pad256] | ticket[1] | q[8] |
    //      offset[N] | cursor[N]  then u16: srcs[E] | fb[N*D] | hb[pad*D] | wt
    int flags_n = ((nblk_scan + 255) / 256) * 256;
    size_t ints = (size_t)3 * n_nodes + flags_n + 9;
    size_t srcs_off = ints * sizeof(int);
    size_t fb_off = (srcs_off + (size_t)n_edges * 2 + 255) & ~(size_t)255;
    size_t hb_off = (fb_off + (size_t)n_nodes * D * 2 + 255) & ~(size_t)255;
    size_t wt_off = hb_off + (size_t)nrows_pad * D * 2;
    size_t need_ultra = wt_off + (size_t)D * D * 2;

    // ---- tier2 layout
    size_t csr_ints = (size_t)3 * n_nodes + 1 + n_edges;
    size_t csr_bytes = csr_ints * sizeof(int);
    size_t t2_hb_off = (csr_bytes + 255) & ~(size_t)255;
    size_t t2_wt_off = t2_hb_off + (size_t)nrows_pad * D * 2;
    size_t need_t2 = t2_wt_off + (size_t)D * D * 2;

    if (n_nodes < 65536 && nblk_scan <= 4096 && ws_size >= need_ultra) {
        int* cnt = (int*)d_ws;
        unsigned int* flags = (unsigned int*)(cnt + n_nodes);
        int* ticket = (int*)(flags + flags_n);
        int* q = ticket + 1;
        int* offset = q + 8;
        int* cursor = offset + n_nodes;
        unsigned short* srcs = (unsigned short*)((char*)d_ws + srcs_off);
        unsigned short* fb = (unsigned short*)((char*)d_ws + fb_off);
        unsigned short* hb = (unsigned short*)((char*)d_ws + hb_off);
        unsigned short* wt = (unsigned short*)((char*)d_ws + wt_off);

        // zero cnt + flags + ticket + q in one memset
        hipMemsetAsync(cnt, 0, ((size_t)n_nodes + flags_n + 9) * sizeof(int),
                       stream);
        k_prep<<<2048, block, 0, stream>>>(dst, cnt, feature, fb, n_edges,
                                           n_nodes * D / 4, W, wt);
        k_scan<<<nblk_scan, block, 0, stream>>>(cnt, offset, cursor, ticket,
                                                flags, n_nodes);
        float scale8 = 8.0f / (float)n_nodes;
        k_fill_xcd<<<1024, block, 0, stream>>>(src, dst, cursor, srcs, q,
                                               n_edges, scale8);
        k_aggregate_u16<<<((size_t)n_nodes * 64 + block - 1) / block, block, 0,
                          stream>>>(fb, srcs, offset, cnt, hb, n_nodes);
        k_finalize_mfma<<<(n_nodes + 127) / 128, block, 0, stream>>>(
            hb, wt, b, out, n_nodes);
    } else if (ws_size >= need_t2) {
        int* cnt = (int*)d_ws;
        int* gtot = cnt + n_nodes;
        int* offset = gtot + 1;
        int* cursor = offset + n_nodes;
        int* srcs = cursor + n_nodes;
        unsigned short* hb = (unsigned short*)((char*)d_ws + t2_hb_off);
        unsigned short* wt = (unsigned short*)((char*)d_ws + t2_wt_off);

        hipMemsetAsync(cnt, 0, (size_t)(n_nodes + 1) * sizeof(int), stream);
        k_hist<<<2048, block, 0, stream>>>(dst, cnt, n_edges);
        k_alloc<<<(n_nodes + block - 1) / block, block, 0, stream>>>(
            cnt, offset, cursor, gtot, n_nodes, W, wt);
        k_fill<<<2048, block, 0, stream>>>(src, dst, cursor, srcs, n_edges);
        k_aggregate_bf16<<<((size_t)n_nodes * 64 + block - 1) / block, block, 0,
                           stream>>>(feature, srcs, offset, cnt, hb, n_nodes);
        k_finalize_mfma<<<(n_nodes + 127) / 128, block, 0, stream>>>(
            hb, wt, b, out, n_nodes);
    } else if (ws_size >= csr_bytes) {
        int* cnt = (int*)d_ws;
        int* gtot = cnt + n_nodes;
        int* offset = gtot + 1;
        int* cursor = offset + n_nodes;
        int* srcs = cursor + n_nodes;

        hipMemsetAsync(cnt, 0, (size_t)(n_nodes + 1) * sizeof(int), stream);
        k_hist<<<2048, block, 0, stream>>>(dst, cnt, n_edges);
        k_alloc<<<(n_nodes + block - 1) / block, block, 0, stream>>>(
            cnt, offset, cursor, gtot, n_nodes, nullptr, nullptr);
        k_fill<<<2048, block, 0, stream>>>(src, dst, cursor, srcs, n_edges);
        k_aggregate_f32<<<((size_t)n_nodes * 64 + block - 1) / block, block, 0,
                          stream>>>(feature, srcs, offset, cnt, out, n_nodes);
        gcn_finalize<<<512, block, 0, stream>>>(out, feature, W, b, nullptr,
                                                n_nodes);
    } else {
        float* deg = (float*)d_ws;
        hipMemsetAsync(out, 0, (size_t)out_size * sizeof(float), stream);
        hipMemsetAsync(deg, 0, (size_t)n_nodes * sizeof(float), stream);
        long long total_threads = (long long)n_edges * 64;
        int grid = (int)((total_threads + block - 1) / block);
        gcn_scatter<<<grid, block, 0, stream>>>(feature, src, dst, out, deg,
                                                n_edges);
        gcn_finalize<<<512, block, 0, stream>>>(out, feature, W, b, deg,
                                                n_nodes);
    }
}

// Round 6
// 205.233 us; speedup vs baseline: 1.2590x; 1.2590x over previous
//
#include <hip/hip_runtime.h>

#define D 128
#define ACHUNK 1024

typedef float f32x4 __attribute__((ext_vector_type(4)));
typedef float f32x8 __attribute__((ext_vector_type(8)));
typedef short s16x8 __attribute__((ext_vector_type(8)));
typedef unsigned short u16x8 __attribute__((ext_vector_type(8)));

static __device__ __forceinline__ unsigned short f2bf(float f) {
    unsigned int u = __float_as_uint(f);
    unsigned int r = (u + 0x7FFFu + ((u >> 16) & 1u)) >> 16;  // RNE
    return (unsigned short)r;
}

// ===========================================================================
// ULTRA tier
// ===========================================================================

// hist (global, 4-batched) + per-partition counts (LDS-aggregated) +
// feature->bf16 + W->Wt bf16, fused
__global__ void k_prep(const int* __restrict__ dst, int* __restrict__ cnt,
                       int* __restrict__ pcnt, const float* __restrict__ feature,
                       unsigned short* __restrict__ fb, int E, int NF4,
                       const float* __restrict__ W,
                       unsigned short* __restrict__ wt, float scale8) {
    __shared__ int lp[8];
    if (threadIdx.x < 8) lp[threadIdx.x] = 0;
    __syncthreads();
    int tid = blockIdx.x * blockDim.x + threadIdx.x;
    int stride = gridDim.x * blockDim.x;
    for (int base = tid * 4; base < E; base += stride * 4) {
        if (base + 4 <= E) {
            int4 d4 = *reinterpret_cast<const int4*>(dst + base);
            #pragma unroll
            for (int u = 0; u < 4; ++u) {
                int d = (&d4.x)[u];
                atomicAdd(&cnt[d], 1);
                int p = min((int)((float)d * scale8), 7);
                atomicAdd(&lp[p], 1);
            }
        } else {
            for (int i = base; i < E; ++i) {
                int d = dst[i];
                atomicAdd(&cnt[d], 1);
                int p = min((int)((float)d * scale8), 7);
                atomicAdd(&lp[p], 1);
            }
        }
    }
    const f32x4* f4 = reinterpret_cast<const f32x4*>(feature);
    ushort4* fb4 = reinterpret_cast<ushort4*>(fb);
    for (int i = tid; i < NF4; i += stride) {
        f32x4 v = f4[i];
        ushort4 o;
        o.x = f2bf(v[0]);
        o.y = f2bf(v[1]);
        o.z = f2bf(v[2]);
        o.w = f2bf(v[3]);
        fb4[i] = o;
    }
    for (int i = tid; i < D * D; i += stride) {
        int n = i >> 7, k = i & 127;
        wt[i] = f2bf(W[k * D + n]);
    }
    __syncthreads();
    if (threadIdx.x < 8 && lp[threadIdx.x])
        atomicAdd(&pcnt[threadIdx.x], lp[threadIdx.x]);
}

// Node-ordered exclusive prefix scan of cnt -> offset/cursor.
// Decoupled lookback, ticket-ordered tiles; deadlock-free.
__global__ __launch_bounds__(256) void k_scan(const int* __restrict__ cnt,
                                              int* __restrict__ offset,
                                              int* __restrict__ cursor,
                                              int* __restrict__ ticket,
                                              unsigned int* __restrict__ flags,
                                              int N) {
    __shared__ int stile;
    __shared__ int wsum[4];
    __shared__ int sexcl;
    if (threadIdx.x == 0) stile = atomicAdd(ticket, 1);
    __syncthreads();
    int tile = stile;
    int i = tile * 256 + threadIdx.x;
    int lane = threadIdx.x & 63;
    int wv = threadIdx.x >> 6;
    int c = (i < N) ? cnt[i] : 0;
    int s = c;
    #pragma unroll
    for (int o = 1; o < 64; o <<= 1) {
        int t = __shfl_up(s, o);
        if (lane >= o) s += t;
    }
    if (lane == 63) wsum[wv] = s;
    __syncthreads();
    int wb = 0;
    for (int k = 0; k < wv; ++k) wb += wsum[k];
    int incl = s + wb;
    int tilesum = wsum[0] + wsum[1] + wsum[2] + wsum[3];
    if (threadIdx.x == 0) {
        if (tile == 0) {
            __atomic_store_n(&flags[0], 0x80000000u | (unsigned)tilesum,
                             __ATOMIC_RELEASE);
            sexcl = 0;
        } else {
            __atomic_store_n(&flags[tile], 0x40000000u | (unsigned)tilesum,
                             __ATOMIC_RELEASE);
            int excl = 0;
            int p = tile - 1;
            while (true) {
                unsigned f;
                do {
                    f = __atomic_load_n(&flags[p], __ATOMIC_ACQUIRE);
                } while (!(f & 0xC0000000u));
                excl += (int)(f & 0x3FFFFFFFu);
                if (f & 0x80000000u) break;
                --p;
            }
            __atomic_store_n(&flags[tile],
                             0x80000000u | (unsigned)(excl + tilesum),
                             __ATOMIC_RELEASE);
            sexcl = excl;
        }
    }
    __syncthreads();
    if (i < N) {
        int base = sexcl + incl - c;
        offset[i] = base;
        cursor[i] = base;
    }
}

// Pass A: split edges into 8 dst-partition buckets of packed (dst16|src16)
// pairs. LDS-staged per chunk (overflow-impossible: 8 x ACHUNK slots), then
// flushed per bucket with one cursor atomic + sequential coalesced stores.
__global__ __launch_bounds__(256) void k_bucket(
    const int* __restrict__ src, const int* __restrict__ dst,
    const int* __restrict__ pcnt, int* __restrict__ pcur,
    unsigned int* __restrict__ pairs, int E, float scale8) {
    __shared__ unsigned int lbuf[8][ACHUNK];
    __shared__ int lc[8];
    int pb[8];
    {
        int run = 0;
        #pragma unroll
        for (int p = 0; p < 8; ++p) {
            pb[p] = run;
            run += pcnt[p];
        }
    }
    int nchunk = (E + ACHUNK - 1) / ACHUNK;
    for (int c = blockIdx.x; c < nchunk; c += gridDim.x) {
        if (threadIdx.x < 8) lc[threadIdx.x] = 0;
        __syncthreads();
        int e0 = c * ACHUNK;
        int e1 = min(E, e0 + ACHUNK);
        int e = e0 + (int)threadIdx.x * 4;
        if (e + 4 <= e1) {
            int4 d4 = *reinterpret_cast<const int4*>(dst + e);
            int4 s4 = *reinterpret_cast<const int4*>(src + e);
            #pragma unroll
            for (int u = 0; u < 4; ++u) {
                int d = (&d4.x)[u];
                int sv = (&s4.x)[u];
                int p = min((int)((float)d * scale8), 7);
                int s = atomicAdd(&lc[p], 1);
                lbuf[p][s] = ((unsigned)d << 16) | (unsigned)sv;
            }
        } else {
            for (int i = e; i < e1; ++i) {
                int d = dst[i];
                int sv = src[i];
                int p = min((int)((float)d * scale8), 7);
                int s = atomicAdd(&lc[p], 1);
                lbuf[p][s] = ((unsigned)d << 16) | (unsigned)sv;
            }
        }
        __syncthreads();
        int wv = threadIdx.x >> 6;
        int lane = threadIdx.x & 63;
        for (int b = wv; b < 8; b += 4) {
            int n = lc[b];
            if (n) {
                int base = 0;
                if (lane == 0) base = atomicAdd(&pcur[b], n);
                base = __shfl(base, 0) + pb[b];
                for (int i = lane; i < n; i += 64) pairs[base + i] = lbuf[b][i];
            }
        }
        __syncthreads();
    }
}

// Pass B: block bid&7 handles partition bid&7 (empirically XCD-local via
// round-robin dispatch; correctness independent of the mapping). Scatter
// src ids into the partition's contiguous srcs window.
__global__ __launch_bounds__(256) void k_fill_part(
    const int* __restrict__ pcnt, const unsigned int* __restrict__ pairs,
    int* __restrict__ cursor, unsigned short* __restrict__ srcs) {
    int part = blockIdx.x & 7;
    int nb = gridDim.x >> 3;
    int slot = blockIdx.x >> 3;
    int pb[8];
    {
        int run = 0;
        #pragma unroll
        for (int p = 0; p < 8; ++p) {
            pb[p] = run;
            run += pcnt[p];
        }
    }
    int base = pb[part];
    int n = pcnt[part];
    for (int i = slot * 256 + (int)threadIdx.x; i < n; i += nb * 256) {
        unsigned pr = pairs[base + i];
        int d = (int)(pr >> 16);
        unsigned short sv = (unsigned short)(pr & 0xFFFFu);
        int pos = atomicAdd(&cursor[d], 1);
        srcs[pos] = sv;
    }
}

static __device__ __forceinline__ void acc_bf16x8(f32x8& acc, u16x8 v) {
    #pragma unroll
    for (int i = 0; i < 8; ++i)
        acc[i] += __uint_as_float(((unsigned int)v[i]) << 16);
}

// aggregate from bf16 feature: one wave per node, 4 edges in flight
__global__ __launch_bounds__(256) void k_aggregate_u16(
    const unsigned short* __restrict__ fb,
    const unsigned short* __restrict__ srcs, const int* __restrict__ offset,
    const int* __restrict__ cnt, unsigned short* __restrict__ hb, int N) {
    int w = (blockIdx.x * blockDim.x + threadIdx.x) >> 6;
    int lane = threadIdx.x & 63;
    if (w >= N) return;
    int sub = lane >> 4;
    int l15 = lane & 15;
    int n = cnt[w];
    if (n == 0) {
        if (sub == 0) {
            u16x8 v = *reinterpret_cast<const u16x8*>(fb + (size_t)w * D + l15 * 8);
            *reinterpret_cast<u16x8*>(hb + (size_t)w * D + l15 * 8) = v;
        }
        return;
    }
    int base = offset[w];
    f32x8 acc = {0.f, 0.f, 0.f, 0.f, 0.f, 0.f, 0.f, 0.f};
    int j = 0;
    for (; j + 8 <= n; j += 8) {
        int s0 = srcs[base + j + sub];
        int s1 = srcs[base + j + 4 + sub];
        u16x8 v0 = *reinterpret_cast<const u16x8*>(fb + (size_t)s0 * D + l15 * 8);
        u16x8 v1 = *reinterpret_cast<const u16x8*>(fb + (size_t)s1 * D + l15 * 8);
        acc_bf16x8(acc, v0);
        acc_bf16x8(acc, v1);
    }
    for (; j < n; j += 4) {
        if (j + sub < n) {
            int s0 = srcs[base + j + sub];
            u16x8 v0 = *reinterpret_cast<const u16x8*>(fb + (size_t)s0 * D + l15 * 8);
            acc_bf16x8(acc, v0);
        }
    }
    #pragma unroll
    for (int i = 0; i < 8; ++i) acc[i] += __shfl_xor(acc[i], 16);
    #pragma unroll
    for (int i = 0; i < 8; ++i) acc[i] += __shfl_xor(acc[i], 32);
    if (sub == 0) {
        float r = 1.f / (float)n;
        u16x8 o;
        #pragma unroll
        for (int i = 0; i < 8; ++i) o[i] = f2bf(acc[i] * r);
        *reinterpret_cast<u16x8*>(hb + (size_t)w * D + l15 * 8) = o;
    }
}

// ===========================================================================
// Finalize GEMM: out = relu(h @ W + b). XOR-swizzled LDS, 16x16x32 MFMA.
// ===========================================================================
__global__ __launch_bounds__(256) void k_finalize_mfma(
    const unsigned short* __restrict__ hb, const unsigned short* __restrict__ Wt,
    const float* __restrict__ b, float* __restrict__ out, int N) {
    __shared__ char lds[65536];

    int t = threadIdx.x;
    int row0 = blockIdx.x * 128;

    #pragma unroll
    for (int i = 0; i < 8; ++i) {
        int chunk = i * 256 + t;
        int row = chunk >> 4;
        int c16 = chunk & 15;
        int ldsoff = row * 256 + ((c16 * 16) ^ ((row & 7) << 4));
        f32x4 v = {0.f, 0.f, 0.f, 0.f};
        int grow = row0 + row;
        if (grow < N)
            v = *reinterpret_cast<const f32x4*>(hb + (size_t)grow * D + c16 * 8);
        *reinterpret_cast<f32x4*>(&lds[ldsoff]) = v;
    }
    #pragma unroll
    for (int i = 0; i < 8; ++i) {
        int chunk = i * 256 + t;
        int row = chunk >> 4;
        int c16 = chunk & 15;
        int ldsoff = 32768 + row * 256 + ((c16 * 16) ^ ((row & 7) << 4));
        f32x4 v = *reinterpret_cast<const f32x4*>(Wt + (size_t)row * D + c16 * 8);
        *reinterpret_cast<f32x4*>(&lds[ldsoff]) = v;
    }
    __syncthreads();

    int wv = t >> 6;
    int l = t & 63;
    int l15 = l & 15;
    int lhi = l >> 4;

    f32x4 acc[2][8];
    #pragma unroll
    for (int m = 0; m < 2; ++m)
        #pragma unroll
        for (int n = 0; n < 8; ++n) acc[m][n] = (f32x4){0.f, 0.f, 0.f, 0.f};

    #pragma unroll
    for (int kk = 0; kk < 4; ++kk) {
        int kb = kk * 64 + lhi * 16;
        s16x8 af[2], bf[8];
        #pragma unroll
        for (int m = 0; m < 2; ++m) {
            int r = wv * 32 + m * 16 + l15;
            af[m] = *reinterpret_cast<const s16x8*>(
                &lds[r * 256 + (kb ^ ((r & 7) << 4))]);
        }
        #pragma unroll
        for (int n = 0; n < 8; ++n) {
            int r = n * 16 + l15;
            bf[n] = *reinterpret_cast<const s16x8*>(
                &lds[32768 + r * 256 + (kb ^ ((r & 7) << 4))]);
        }
        #pragma unroll
        for (int m = 0; m < 2; ++m)
            #pragma unroll
            for (int n = 0; n < 8; ++n)
                acc[m][n] = __builtin_amdgcn_mfma_f32_16x16x32_bf16(
                    af[m], bf[n], acc[m][n], 0, 0, 0);
    }

    #pragma unroll
    for (int n = 0; n < 8; ++n) {
        int col = n * 16 + l15;
        float bv = b[col];
        #pragma unroll
        for (int m = 0; m < 2; ++m) {
            int rbase = row0 + wv * 32 + m * 16 + lhi * 4;
            #pragma unroll
            for (int j = 0; j < 4; ++j) {
                int row = rbase + j;
                if (row < N)
                    out[(size_t)row * D + col] = fmaxf(acc[m][n][j] + bv, 0.f);
            }
        }
    }
}

// ===========================================================================
// Tier-2 kernels (fp32-feature gather, int srcs, unordered alloc)
// ===========================================================================
__global__ void k_hist(const int* __restrict__ dst, int* __restrict__ cnt,
                       int E) {
    int stride = gridDim.x * blockDim.x;
    for (int i = blockIdx.x * blockDim.x + threadIdx.x; i < E; i += stride)
        atomicAdd(&cnt[dst[i]], 1);
}

__global__ void k_alloc(const int* __restrict__ cnt, int* __restrict__ offset,
                        int* __restrict__ cursor, int* __restrict__ gtot,
                        int N, const float* __restrict__ W,
                        unsigned short* __restrict__ wt) {
    int i = blockIdx.x * blockDim.x + threadIdx.x;
    int lane = threadIdx.x & 63;
    if (W && i < D * D) {
        int n = i >> 7, k = i & 127;
        wt[i] = f2bf(W[k * D + n]);
    }
    int c = (i < N) ? cnt[i] : 0;
    int s = c;
    #pragma unroll
    for (int o = 1; o < 64; o <<= 1) {
        int t = __shfl_up(s, o);
        if (lane >= o) s += t;
    }
    int wavesum = __shfl(s, 63);
    int base = 0;
    if (lane == 0) base = atomicAdd(gtot, wavesum);
    base = __shfl(base, 0);
    if (i < N) {
        int off = base + s - c;
        offset[i] = off;
        cursor[i] = off;
    }
}

__global__ void k_fill(const int* __restrict__ src, const int* __restrict__ dst,
                       int* __restrict__ cursor, int* __restrict__ srcs,
                       int E) {
    int stride = gridDim.x * blockDim.x;
    for (int i = blockIdx.x * blockDim.x + threadIdx.x; i < E; i += stride) {
        int d = dst[i];
        int p = atomicAdd(&cursor[d], 1);
        srcs[p] = src[i];
    }
}

__global__ __launch_bounds__(256) void k_aggregate_bf16(
    const float* __restrict__ feature, const int* __restrict__ srcs,
    const int* __restrict__ offset, const int* __restrict__ cnt,
    unsigned short* __restrict__ hb, int N) {
    int w = (blockIdx.x * blockDim.x + threadIdx.x) >> 6;
    int lane = threadIdx.x & 63;
    if (w >= N) return;
    int sub = lane >> 5;
    int c0 = (lane & 31) * 4;
    int n = cnt[w];
    f32x4 acc = {0.f, 0.f, 0.f, 0.f};
    if (n == 0) {
        if (sub == 0)
            acc = *reinterpret_cast<const f32x4*>(feature + (size_t)w * D + c0);
    } else {
        int base = offset[w];
        int j = 0;
        for (; j + 4 <= n; j += 4) {
            int s0 = srcs[base + j + sub];
            int s1 = srcs[base + j + 2 + sub];
            f32x4 v0 = *reinterpret_cast<const f32x4*>(feature + (size_t)s0 * D + c0);
            f32x4 v1 = *reinterpret_cast<const f32x4*>(feature + (size_t)s1 * D + c0);
            acc += v0 + v1;
        }
        for (; j < n; j += 2) {
            if (j + sub < n) {
                int s0 = srcs[base + j + sub];
                f32x4 v0 = *reinterpret_cast<const f32x4*>(feature + (size_t)s0 * D + c0);
                acc += v0;
            }
        }
    }
    #pragma unroll
    for (int i = 0; i < 4; ++i) acc[i] += __shfl_xor(acc[i], 32);
    if (n > 1) {
        float r = 1.f / (float)n;
        #pragma unroll
        for (int i = 0; i < 4; ++i) acc[i] *= r;
    }
    if (sub == 0) {
        ushort4 o;
        o.x = f2bf(acc[0]);
        o.y = f2bf(acc[1]);
        o.z = f2bf(acc[2]);
        o.w = f2bf(acc[3]);
        *reinterpret_cast<ushort4*>(hb + (size_t)w * D + c0) = o;
    }
}

// ===========================================================================
// Tier-3/4 fallbacks
// ===========================================================================
__global__ __launch_bounds__(256) void k_aggregate_f32(
    const float* __restrict__ feature, const int* __restrict__ srcs,
    const int* __restrict__ offset, const int* __restrict__ cnt,
    float* __restrict__ h, int N) {
    int w = (blockIdx.x * blockDim.x + threadIdx.x) >> 6;
    int lane = threadIdx.x & 63;
    if (w >= N) return;
    int n = cnt[w];
    float2 acc = make_float2(0.f, 0.f);
    if (n == 0) {
        acc = *reinterpret_cast<const float2*>(feature + (size_t)w * D + lane * 2);
    } else {
        int base = offset[w];
        for (int j = 0; j < n; ++j) {
            int s0 = srcs[base + j];
            float2 v0 = *reinterpret_cast<const float2*>(feature + (size_t)s0 * D + lane * 2);
            acc.x += v0.x;
            acc.y += v0.y;
        }
        float r = 1.f / (float)n;
        acc.x *= r;
        acc.y *= r;
    }
    *reinterpret_cast<float2*>(h + (size_t)w * D + lane * 2) = acc;
}

__global__ void gcn_scatter(const float* __restrict__ feature,
                            const int* __restrict__ src,
                            const int* __restrict__ dst,
                            float* __restrict__ agg,
                            float* __restrict__ deg, int n_edges) {
    int gid = blockIdx.x * blockDim.x + threadIdx.x;
    int e = gid >> 6;
    int lane = gid & 63;
    if (e >= n_edges) return;
    int s = src[e];
    int d = dst[e];
    const float2 v =
        *reinterpret_cast<const float2*>(feature + (size_t)s * D + lane * 2);
    float* o = agg + (size_t)d * D + lane * 2;
    atomicAdd(o, v.x);
    atomicAdd(o + 1, v.y);
    if (lane == 0) atomicAdd(deg + d, 1.0f);
}

__global__ __launch_bounds__(256, 2) void gcn_finalize(
    float* __restrict__ inout, const float* __restrict__ feature,
    const float* __restrict__ W, const float* __restrict__ b,
    const float* __restrict__ deg, int n_nodes) {
    __shared__ float Ws[D * D];
    __shared__ float bs[D];
    __shared__ float hs[4][4][D];

    for (int i = threadIdx.x; i < (D * D) / 4; i += blockDim.x)
        reinterpret_cast<float4*>(Ws)[i] = reinterpret_cast<const float4*>(W)[i];
    if (threadIdx.x < D) bs[threadIdx.x] = b[threadIdx.x];
    __syncthreads();

    int wave = threadIdx.x >> 6;
    int lane = threadIdx.x & 63;
    int gwave = (blockIdx.x * blockDim.x + threadIdx.x) >> 6;
    int nwaves = (gridDim.x * blockDim.x) >> 6;
    int ngroups = (n_nodes + 3) / 4;

    for (int g = gwave; g < ngroups; g += nwaves) {
        int row0 = g * 4;
        #pragma unroll
        for (int r = 0; r < 4; ++r) {
            int row = row0 + r;
            if (row < n_nodes) {
                float2 h2;
                if (deg) {
                    float dg = deg[row];
                    if (dg > 0.f) {
                        float2 a = *reinterpret_cast<const float2*>(
                            inout + (size_t)row * D + lane * 2);
                        float rd = 1.f / dg;
                        h2.x = a.x * rd;
                        h2.y = a.y * rd;
                    } else {
                        h2 = *reinterpret_cast<const float2*>(
                            feature + (size_t)row * D + lane * 2);
                    }
                } else {
                    h2 = *reinterpret_cast<const float2*>(
                        inout + (size_t)row * D + lane * 2);
                }
                reinterpret_cast<float2*>(hs[wave][r])[lane] = h2;
            }
        }
        float acc2[4][2];
        #pragma unroll
        for (int r = 0; r < 4; ++r) {
            acc2[r][0] = bs[lane];
            acc2[r][1] = bs[lane + 64];
        }
        #pragma unroll 4
        for (int k = 0; k < D; ++k) {
            float w0 = Ws[k * D + lane];
            float w1 = Ws[k * D + lane + 64];
            #pragma unroll
            for (int r = 0; r < 4; ++r) {
                float hk = hs[wave][r][k];
                acc2[r][0] = fmaf(hk, w0, acc2[r][0]);
                acc2[r][1] = fmaf(hk, w1, acc2[r][1]);
            }
        }
        #pragma unroll
        for (int r = 0; r < 4; ++r) {
            int row = row0 + r;
            if (row < n_nodes) {
                inout[(size_t)row * D + lane] = fmaxf(acc2[r][0], 0.f);
                inout[(size_t)row * D + lane + 64] = fmaxf(acc2[r][1], 0.f);
            }
        }
    }
}

extern "C" void kernel_launch(void* const* d_in, const int* in_sizes, int n_in,
                              void* d_out, int out_size, void* d_ws,
                              size_t ws_size, hipStream_t stream) {
    const float* feature = (const float*)d_in[0];
    const float* W = (const float*)d_in[1];
    const float* b = (const float*)d_in[2];
    const int* src = (const int*)d_in[3];
    const int* dst = (const int*)d_in[4];
    int n_edges = in_sizes[3];
    int n_nodes = in_sizes[0] / D;

    float* out = (float*)d_out;
    int block = 256;
    int nrows_pad = ((n_nodes + 127) / 128) * 128;
    int nblk_scan = (n_nodes + 255) / 256;

    // ---- ULTRA layout (ints): cnt[N] | flags[padded] | ticket[1] | pcnt[8] |
    //      pcur[8] | offset[N] | cursor[N] | pairs u32[E]
    //      then u16: srcs[E] | fb[N*D] | hb[pad*D] | wt[D*D]
    int flags_n = ((nblk_scan + 255) / 256) * 256;
    size_t ints = (size_t)3 * n_nodes + flags_n + 17 + n_edges;
    size_t srcs_off = ints * sizeof(int);
    size_t fb_off = (srcs_off + (size_t)n_edges * 2 + 255) & ~(size_t)255;
    size_t hb_off = (fb_off + (size_t)n_nodes * D * 2 + 255) & ~(size_t)255;
    size_t wt_off = hb_off + (size_t)nrows_pad * D * 2;
    size_t need_ultra = wt_off + (size_t)D * D * 2;

    // ---- tier2 layout
    size_t csr_ints = (size_t)3 * n_nodes + 1 + n_edges;
    size_t csr_bytes = csr_ints * sizeof(int);
    size_t t2_hb_off = (csr_bytes + 255) & ~(size_t)255;
    size_t t2_wt_off = t2_hb_off + (size_t)nrows_pad * D * 2;
    size_t need_t2 = t2_wt_off + (size_t)D * D * 2;

    if (n_nodes < 65536 && nblk_scan <= 4096 && ws_size >= need_ultra) {
        int* cnt = (int*)d_ws;
        unsigned int* flags = (unsigned int*)(cnt + n_nodes);
        int* ticket = (int*)(flags + flags_n);
        int* pcnt = ticket + 1;
        int* pcur = pcnt + 8;
        int* offset = pcur + 8;
        int* cursor = offset + n_nodes;
        unsigned int* pairs = (unsigned int*)(cursor + n_nodes);
        unsigned short* srcs = (unsigned short*)((char*)d_ws + srcs_off);
        unsigned short* fb = (unsigned short*)((char*)d_ws + fb_off);
        unsigned short* hb = (unsigned short*)((char*)d_ws + hb_off);
        unsigned short* wt = (unsigned short*)((char*)d_ws + wt_off);

        float scale8 = 8.0f / (float)n_nodes;

        // zero cnt + flags + ticket + pcnt + pcur in one memset
        hipMemsetAsync(cnt, 0, ((size_t)n_nodes + flags_n + 17) * sizeof(int),
                       stream);
        k_prep<<<2048, block, 0, stream>>>(dst, cnt, pcnt, feature, fb, n_edges,
                                           n_nodes * D / 4, W, wt, scale8);
        k_scan<<<nblk_scan, block, 0, stream>>>(cnt, offset, cursor, ticket,
                                                flags, n_nodes);
        int nchunk = (n_edges + ACHUNK - 1) / ACHUNK;
        k_bucket<<<min(nchunk, 2048), block, 0, stream>>>(src, dst, pcnt, pcur,
                                                          pairs, n_edges,
                                                          scale8);
        k_fill_part<<<1024, block, 0, stream>>>(pcnt, pairs, cursor, srcs);
        k_aggregate_u16<<<((size_t)n_nodes * 64 + block - 1) / block, block, 0,
                          stream>>>(fb, srcs, offset, cnt, hb, n_nodes);
        k_finalize_mfma<<<(n_nodes + 127) / 128, block, 0, stream>>>(
            hb, wt, b, out, n_nodes);
    } else if (ws_size >= need_t2) {
        int* cnt = (int*)d_ws;
        int* gtot = cnt + n_nodes;
        int* offset = gtot + 1;
        int* cursor = offset + n_nodes;
        int* srcs = cursor + n_nodes;
        unsigned short* hb = (unsigned short*)((char*)d_ws + t2_hb_off);
        unsigned short* wt = (unsigned short*)((char*)d_ws + t2_wt_off);

        hipMemsetAsync(cnt, 0, (size_t)(n_nodes + 1) * sizeof(int), stream);
        k_hist<<<2048, block, 0, stream>>>(dst, cnt, n_edges);
        k_alloc<<<(n_nodes + block - 1) / block, block, 0, stream>>>(
            cnt, offset, cursor, gtot, n_nodes, W, wt);
        k_fill<<<2048, block, 0, stream>>>(src, dst, cursor, srcs, n_edges);
        k_aggregate_bf16<<<((size_t)n_nodes * 64 + block - 1) / block, block, 0,
                           stream>>>(feature, srcs, offset, cnt, hb, n_nodes);
        k_finalize_mfma<<<(n_nodes + 127) / 128, block, 0, stream>>>(
            hb, wt, b, out, n_nodes);
    } else if (ws_size >= csr_bytes) {
        int* cnt = (int*)d_ws;
        int* gtot = cnt + n_nodes;
        int* offset = gtot + 1;
        int* cursor = offset + n_nodes;
        int* srcs = cursor + n_nodes;

        hipMemsetAsync(cnt, 0, (size_t)(n_nodes + 1) * sizeof(int), stream);
        k_hist<<<2048, block, 0, stream>>>(dst, cnt, n_edges);
        k_alloc<<<(n_nodes + block - 1) / block, block, 0, stream>>>(
            cnt, offset, cursor, gtot, n_nodes, nullptr, nullptr);
        k_fill<<<2048, block, 0, stream>>>(src, dst, cursor, srcs, n_edges);
        k_aggregate_f32<<<((size_t)n_nodes * 64 + block - 1) / block, block, 0,
                          stream>>>(feature, srcs, offset, cnt, out, n_nodes);
        gcn_finalize<<<512, block, 0, stream>>>(out, feature, W, b, nullptr,
                                                n_nodes);
    } else {
        float* deg = (float*)d_ws;
        hipMemsetAsync(out, 0, (size_t)out_size * sizeof(float), stream);
        hipMemsetAsync(deg, 0, (size_t)n_nodes * sizeof(float), stream);
        long long total_threads = (long long)n_edges * 64;
        int grid = (int)((total_threads + block - 1) / block);
        gcn_scatter<<<grid, block, 0, stream>>>(feature, src, dst, out, deg,
                                                n_edges);
        gcn_finalize<<<512, block, 0, stream>>>(out, feature, W, b, deg,
                                                n_nodes);
    }
}